// Round 7
// baseline (706.689 us; speedup 1.0000x reference)
//
#include <hip/hip_runtime.h>
#include <hip/hip_bf16.h>

#define BB 64
#define NN 6272      // H*W*C = 196*32
#define OO 10
#define SSL 14       // grid.x: hi
#define NSTEP 14     // wi steps
#define TPB 640      // two 320-thread tiles: (b, hi) and (b+32, hi)
#define EPSF 1e-9f

// workspace offsets (floats)
#define ACC_PER_IT 21120            // B*O*33
#define OFF_ACC 0                   // 3 * 21120
#define OFF_MU  63360               // 2 * B*O*16
#define OFF_IV  83840               // 2 * B*O*16
#define OFF_BI  104320              // 2 * B*O

// R7: R3's proven spill-free per-thread structure (votes once, per-step
// barrier, logit exchange via 3KB LDS, width-32 butterfly epilogue), but
// 640-thread blocks = TWO independent 320-thread (b,hi) tiles. Evidence
// (R1-R6): never more than ~8 waves/CU resident regardless of LDS/VGPR;
// duration ~ per-wave serial time x 3.5 sequential blocks. Packing 10
// waves/block doubles resident waves even at 1-2 blocks/CU. Grid 448
// blocks -> 1.75/CU. Plus: pose prefetch overlapping the barrier, and
// tree max/sum in softmax (depth 4 vs 9/10 chains).
__global__ __launch_bounds__(TPB, 5) void fc_pass(
    const float* __restrict__ pose, const float* __restrict__ actv,
    const float* __restrict__ wgt,
    const float* __restrict__ muIn, const float* __restrict__ ivIn,
    const float* __restrict__ biIn,
    float* __restrict__ acc, int iter)
{
    __shared__ float logitL[2][2][32 * 11];   // [tile][parity][c*11+o]

    const int t    = threadIdx.x;
    const int half = (t >= 320) ? 1 : 0;      // tile select
    const int tl   = t - half * 320;          // tile-local 0..319
    const int c    = tl & 31;
    const int o    = tl >> 5;                 // 0..9
    const int ss   = blockIdx.x;              // == hi
    const int b    = blockIdx.y + half * 32;  // tile A: b, tile B: b+32

    // W[c][o] 4x4 in registers, wr[j*4+k]
    float wr[16];
    {
        const float4* wp = (const float4*)(wgt + ((c * OO + o) << 4));
        float4 a0 = wp[0], a1 = wp[1], a2 = wp[2], a3 = wp[3];
        wr[0]=a0.x; wr[1]=a0.y; wr[2]=a0.z; wr[3]=a0.w;
        wr[4]=a1.x; wr[5]=a1.y; wr[6]=a1.z; wr[7]=a1.w;
        wr[8]=a2.x; wr[9]=a2.y; wr[10]=a2.z; wr[11]=a2.w;
        wr[12]=a3.x; wr[13]=a3.y; wr[14]=a3.z; wr[15]=a3.w;
    }

    float mu[16], iv[16], bias = 0.f;
    if (iter > 0) {
        const float4* mp = (const float4*)(muIn + (((size_t)b * OO + o) << 4));
        const float4* vp = (const float4*)(ivIn + (((size_t)b * OO + o) << 4));
        float4 m0=mp[0], m1=mp[1], m2=mp[2], m3=mp[3];
        mu[0]=m0.x; mu[1]=m0.y; mu[2]=m0.z; mu[3]=m0.w;
        mu[4]=m1.x; mu[5]=m1.y; mu[6]=m1.z; mu[7]=m1.w;
        mu[8]=m2.x; mu[9]=m2.y; mu[10]=m2.z; mu[11]=m2.w;
        mu[12]=m3.x; mu[13]=m3.y; mu[14]=m3.z; mu[15]=m3.w;
        float4 v0=vp[0], v1=vp[1], v2=vp[2], v3=vp[3];
        iv[0]=v0.x; iv[1]=v0.y; iv[2]=v0.z; iv[3]=v0.w;
        iv[4]=v1.x; iv[5]=v1.y; iv[6]=v1.z; iv[7]=v1.w;
        iv[8]=v2.x; iv[9]=v2.y; iv[10]=v2.z; iv[11]=v2.w;
        iv[12]=v3.x; iv[13]=v3.y; iv[14]=v3.z; iv[15]=v3.w;
        bias = biIn[b * OO + o];
    }

    float S1[16], S2[16], S0 = 0.f;
    #pragma unroll
    for (int d = 0; d < 16; d++) { S1[d] = 0.f; S2[d] = 0.f; }

    const size_t rowB = (size_t)b * NN + ss * 448 + c;   // + s*32
    const float offh = (ss + 0.5f) * (1.0f / 14.0f);

    // prefetch step 0
    float4 q0, q1, q2, q3;  float a;
    {
        const float4* pp = (const float4*)(pose + rowB * 16);
        q0 = pp[0]; q1 = pp[1]; q2 = pp[2]; q3 = pp[3];
        a = actv[rowB];
    }

    for (int s = 0; s < NSTEP; s++) {
        const float offw = (s + 0.5f) * (1.0f / 14.0f);

        float p[16];
        p[0]=q0.x; p[1]=q0.y; p[2]=q0.z; p[3]=q0.w;
        p[4]=q1.x; p[5]=q1.y; p[6]=q1.z; p[7]=q1.w;
        p[8]=q2.x; p[9]=q2.y; p[10]=q2.z; p[11]=q2.w;
        p[12]=q3.x; p[13]=q3.y; p[14]=q3.z; p[15]=q3.w;
        const float av = a;

        // votes (coord-addition folded in) -- computed ONCE per step
        float v[16];
        #pragma unroll
        for (int ii = 0; ii < 4; ii++) {
            #pragma unroll
            for (int kk = 0; kk < 4; kk++) {
                float vv = fmaf(p[ii*4+0], wr[0*4+kk],
                           fmaf(p[ii*4+1], wr[1*4+kk],
                           fmaf(p[ii*4+2], wr[2*4+kk],
                                p[ii*4+3] * wr[3*4+kk])));
                if (ii == 0 && kk == 3) vv += offw;
                if (ii == 1 && kk == 3) vv += offh;
                v[ii*4+kk] = vv;
            }
        }

        float rr;
        if (iter > 0) {
            // sq as 4 independent partials (shorter dependent chain)
            float sqa = 0.f, sqb = 0.f, sqc = 0.f, sqd = 0.f;
            #pragma unroll
            for (int ii = 0; ii < 4; ii++) {
                float d0 = v[ii*4+0] - mu[ii*4+0];
                float d1 = v[ii*4+1] - mu[ii*4+1];
                float d2 = v[ii*4+2] - mu[ii*4+2];
                float d3 = v[ii*4+3] - mu[ii*4+3];
                sqa = fmaf(d0*d0, iv[ii*4+0], sqa);
                sqb = fmaf(d1*d1, iv[ii*4+1], sqb);
                sqc = fmaf(d2*d2, iv[ii*4+2], sqc);
                sqd = fmaf(d3*d3, iv[ii*4+3], sqd);
            }
            const float lg = bias - 0.5f * ((sqa + sqb) + (sqc + sqd));
            logitL[half][s & 1][c * 11 + o] = lg;

            // prefetch next step's pose row while the barrier drains
            if (s + 1 < NSTEP) {
                const float4* np = (const float4*)(pose + (rowB + (size_t)(s+1)*32) * 16);
                q0 = np[0]; q1 = np[1]; q2 = np[2]; q3 = np[3];
                a = actv[rowB + (size_t)(s+1)*32];
            }
            __syncthreads();

            float lgs[OO];
            #pragma unroll
            for (int j = 0; j < OO; j++) lgs[j] = logitL[half][s & 1][c * 11 + j];
            // tree max (depth 4)
            float m01 = fmaxf(lgs[0], lgs[1]), m23 = fmaxf(lgs[2], lgs[3]);
            float m45 = fmaxf(lgs[4], lgs[5]), m67 = fmaxf(lgs[6], lgs[7]);
            float m89 = fmaxf(lgs[8], lgs[9]);
            float mx = fmaxf(fmaxf(fmaxf(m01, m23), fmaxf(m45, m67)), m89);
            // exps (independent), own-select, tree sum
            float ef[OO];
            #pragma unroll
            for (int j = 0; j < OO; j++) ef[j] = __expf(lgs[j] - mx);
            float own = ef[0];
            #pragma unroll
            for (int j = 1; j < OO; j++) own = (j == o) ? ef[j] : own;
            float s01 = ef[0]+ef[1], s23 = ef[2]+ef[3], s45 = ef[4]+ef[5];
            float s67 = ef[6]+ef[7], s89 = ef[8]+ef[9];
            const float sum = ((s01+s23) + (s45+s67)) + s89;
            rr = own * av / sum;
        } else {
            if (s + 1 < NSTEP) {
                const float4* np = (const float4*)(pose + (rowB + (size_t)(s+1)*32) * 16);
                q0 = np[0]; q1 = np[1]; q2 = np[2]; q3 = np[3];
                a = actv[rowB + (size_t)(s+1)*32];
            }
            rr = 0.1f * av;
        }

        #pragma unroll
        for (int d = 0; d < 16; d++) {
            const float rv = rr * v[d];
            S1[d] += rv;
            S2[d] = fmaf(rv, v[d], S2[d]);
        }
        S0 += rr;
    }

    // epilogue: width-32 butterfly (proven spill-free in R3) + atomics
    float* ab = acc + ((size_t)b * OO + o) * 33;
    float myred = 0.f;
    #pragma unroll
    for (int k = 0; k < 32; k++) {
        float tot = (k < 16) ? S1[k] : S2[k - 16];
        #pragma unroll
        for (int msk = 16; msk >= 1; msk >>= 1)
            tot += __shfl_xor(tot, msk, 32);
        if (c == k) myred = tot;
    }
    {
        float tot = S0;
        #pragma unroll
        for (int msk = 16; msk >= 1; msk >>= 1)
            tot += __shfl_xor(tot, msk, 32);
        if (c == 0) atomicAdd(&ab[32], tot);
    }
    atomicAdd(&ab[c], myred);
}

__global__ __launch_bounds__(256) void fc_stats(
    const float* __restrict__ acc, const float* __restrict__ beta_a,
    const float* __restrict__ beta_u,
    float* __restrict__ muOut, float* __restrict__ ivOut, float* __restrict__ biOut,
    float* __restrict__ out, float inv_temp, int final_it)
{
    const int t = threadIdx.x;
    const int b = blockIdx.x;
    if (t >= 160) return;
    const int o = t >> 4, d = t & 15;
    const float* ab = acc + ((size_t)b * OO + o) * 33;
    const float S1 = ab[d], S2 = ab[16 + d], S0 = ab[32];
    const float rs = S0 + EPSF;
    const float mu = S1 / rs;
    float vraw = fmaf(mu * mu, S0, fmaf(-2.f * mu, S1, S2));
    vraw = fmaxf(vraw, 0.f);
    const float var = vraw / rs + EPSF;
    const float lv = __logf(var);
    float sv = lv;
    #pragma unroll
    for (int off = 8; off >= 1; off >>= 1) sv += __shfl_xor(sv, off, 16);
    const float cost = rs * fmaf(0.5f, sv, 16.f * beta_u[o]);
    const float av = 1.f / (1.f + __expf(-inv_temp * (beta_a[o] - cost)));
    if (!final_it) {
        muOut[((size_t)b * OO + o) * 16 + d] = mu;
        ivOut[((size_t)b * OO + o) * 16 + d] = 1.f / var;
        if (d == 0) biOut[b * OO + o] = __logf(av + EPSF) - 0.5f * sv;
    } else {
        out[((size_t)b * OO + o) * 16 + d] = mu;               // pose_out (B,O,16)
        if (d == 0) out[BB * OO * 16 + b * OO + o] = av;       // act_out (B,O)
    }
}

extern "C" void kernel_launch(void* const* d_in, const int* in_sizes, int n_in,
                              void* d_out, int out_size, void* d_ws, size_t ws_size,
                              hipStream_t stream) {
    const float* pose   = (const float*)d_in[0];
    const float* actv   = (const float*)d_in[1];
    const float* wgt    = (const float*)d_in[2];
    const float* beta_a = (const float*)d_in[3];
    const float* beta_u = (const float*)d_in[4];
    float* out = (float*)d_out;
    float* ws  = (float*)d_ws;

    hipMemsetAsync(ws + OFF_ACC, 0, (size_t)3 * ACC_PER_IT * sizeof(float), stream);

    float* acc0 = ws + OFF_ACC;
    float* acc1 = ws + OFF_ACC + ACC_PER_IT;
    float* acc2 = ws + OFF_ACC + 2 * ACC_PER_IT;
    float* mu0 = ws + OFF_MU;            float* mu1 = ws + OFF_MU + 10240;
    float* iv0 = ws + OFF_IV;            float* iv1 = ws + OFF_IV + 10240;
    float* bi0 = ws + OFF_BI;            float* bi1 = ws + OFF_BI + 640;

    dim3 pgrid(SSL, 32), pblk(TPB);   // 32 b-pairs x 14 hi = 448 blocks
    fc_pass<<<pgrid, pblk, 0, stream>>>(pose, actv, wgt, nullptr, nullptr, nullptr, acc0, 0);
    fc_stats<<<BB, 256, 0, stream>>>(acc0, beta_a, beta_u, mu0, iv0, bi0, out, 1.0f, 0);
    fc_pass<<<pgrid, pblk, 0, stream>>>(pose, actv, wgt, mu0, iv0, bi0, acc1, 1);
    fc_stats<<<BB, 256, 0, stream>>>(acc1, beta_a, beta_u, mu1, iv1, bi1, out, 2.0f, 0);
    fc_pass<<<pgrid, pblk, 0, stream>>>(pose, actv, wgt, mu1, iv1, bi1, acc2, 2);
    fc_stats<<<BB, 256, 0, stream>>>(acc2, beta_a, beta_u, nullptr, nullptr, nullptr, out, 3.0f, 1);
}

// Round 8
// 223.012 us; speedup vs baseline: 3.1688x; 3.1688x over previous
//
#include <hip/hip_runtime.h>
#include <hip/hip_bf16.h>

#define BB 64
#define NN 6272      // H*W*C = 196*32
#define OO 10
#define SSL 14       // fc_pass grid.x (hi); 448 n per block
#define NSTEP 14     // wi steps per block
#define TPB 320      // 32 c x 10 o
#define EPSF 1e-9f

// workspace offsets (floats)
#define ACC_PER_IT 21120            // B*O*33
#define OFF_ACC 0                   // 3 * 21120
#define OFF_MU  63360               // 2 * B*O*16
#define OFF_IV  83840               // 2 * B*O*16
#define OFF_BI  104320              // 2 * B*O

// ---------------- iter-0 specialized pass ----------------
// rr = 0.1*a is o-independent and votes are linear in pose, so
// S1/S2/S0 per (b,o) are exact functionals of 69 per-(b,c) moments:
// A1[16]=S ra*p, M_i[10x4]=S ra*p_i p_i^T, Vw[4]=S ra*offw*p0,
// Vh[4]=S ra*offh*p1, S0,Uw,Uh,sw2,sh2. Accumulate moments (91 FMA/row
// vs ~1150 across 10 o-threads in the generic pass), reduce, transform
// with W in-block, atomically add into the SAME acc[33] layout.
__global__ __launch_bounds__(TPB, 3) void fc_pass0(
    const float* __restrict__ pose, const float* __restrict__ actv,
    const float* __restrict__ wgt, float* __restrict__ acc)
{
    __shared__ float smem0[5 * 2208];       // [wave][c][69] slices, 44160 B

    const int t = threadIdx.x;
    const int lane = t & 63;
    const int wv = t >> 6;                  // 0..4
    const int c = lane & 31;
    const int slot = t >> 5;                // 0..9
    const int chunk = blockIdx.x;           // 0..6 (28 hw rows each)
    const int b = blockIdx.y;

    float A1[16], M[40], Vw[4], Vh[4];
    float S0 = 0.f, Uw = 0.f, Uh = 0.f, sw2 = 0.f, sh2 = 0.f;
    #pragma unroll
    for (int k = 0; k < 16; k++) A1[k] = 0.f;
    #pragma unroll
    for (int k = 0; k < 40; k++) M[k] = 0.f;
    #pragma unroll
    for (int k = 0; k < 4; k++) { Vw[k] = 0.f; Vh[k] = 0.f; }

    for (int r = 0; r < 3; r++) {
        const int hl = slot + 10 * r;
        if (hl >= 28) break;                 // slots 8,9 do 2 rows
        const int hw = chunk * 28 + hl;
        const int hi = hw / 14;
        const int wi = hw - hi * 14;
        const float offw = (wi + 0.5f) * (1.0f / 14.0f);
        const float offh = (hi + 0.5f) * (1.0f / 14.0f);
        const size_t row = (size_t)b * NN + (hw << 5) + c;

        const float4* pp = (const float4*)(pose + row * 16);
        float4 q0 = pp[0], q1 = pp[1], q2 = pp[2], q3 = pp[3];
        const float a = actv[row];
        const float ra = 0.1f * a;
        const float raw = ra * offw, rah = ra * offh;
        S0 += ra; Uw += raw; Uh += rah;
        sw2 = fmaf(raw, offw, sw2); sh2 = fmaf(rah, offh, sh2);

        #define FOLD_I(qq, i)                                              \
        {                                                                  \
            const float x = qq.x, y = qq.y, z = qq.z, w = qq.w;            \
            const float t0 = ra * x, t1 = ra * y, t2 = ra * z, t3 = ra * w;\
            A1[i*4+0] += t0; A1[i*4+1] += t1;                              \
            A1[i*4+2] += t2; A1[i*4+3] += t3;                              \
            M[i*10+0] = fmaf(t0, x, M[i*10+0]);                            \
            M[i*10+1] = fmaf(t0, y, M[i*10+1]);                            \
            M[i*10+2] = fmaf(t0, z, M[i*10+2]);                            \
            M[i*10+3] = fmaf(t0, w, M[i*10+3]);                            \
            M[i*10+4] = fmaf(t1, y, M[i*10+4]);                            \
            M[i*10+5] = fmaf(t1, z, M[i*10+5]);                            \
            M[i*10+6] = fmaf(t1, w, M[i*10+6]);                            \
            M[i*10+7] = fmaf(t2, z, M[i*10+7]);                            \
            M[i*10+8] = fmaf(t2, w, M[i*10+8]);                            \
            M[i*10+9] = fmaf(t3, w, M[i*10+9]);                            \
        }
        FOLD_I(q0, 0) FOLD_I(q1, 1) FOLD_I(q2, 2) FOLD_I(q3, 3)
        #undef FOLD_I
        Vw[0] = fmaf(raw, q0.x, Vw[0]); Vw[1] = fmaf(raw, q0.y, Vw[1]);
        Vw[2] = fmaf(raw, q0.z, Vw[2]); Vw[3] = fmaf(raw, q0.w, Vw[3]);
        Vh[0] = fmaf(rah, q1.x, Vh[0]); Vh[1] = fmaf(rah, q1.y, Vh[1]);
        Vh[2] = fmaf(rah, q1.z, Vh[2]); Vh[3] = fmaf(rah, q1.w, Vh[3]);
    }

    // fold slot pairs (lane c <- lane c+32) and write per-wave slice
    float* myrow = &smem0[wv * 2208 + c * 69];
    #define FOLDW(arr, n, base)                                            \
    _Pragma("unroll")                                                      \
    for (int k2 = 0; k2 < n; k2++) {                                       \
        float x = arr[k2] + __shfl_xor(arr[k2], 32, 64);                   \
        if (lane < 32) myrow[base + k2] = x;                               \
    }
    FOLDW(A1, 16, 0) FOLDW(M, 40, 16) FOLDW(Vw, 4, 56) FOLDW(Vh, 4, 60)
    #undef FOLDW
    {
        float x0 = S0 + __shfl_xor(S0, 32, 64);
        float x1 = Uw + __shfl_xor(Uw, 32, 64);
        float x2 = Uh + __shfl_xor(Uh, 32, 64);
        float x3 = sw2 + __shfl_xor(sw2, 32, 64);
        float x4 = sh2 + __shfl_xor(sh2, 32, 64);
        if (lane < 32) {
            myrow[64] = x0; myrow[65] = x1; myrow[66] = x2;
            myrow[67] = x3; myrow[68] = x4;
        }
    }
    __syncthreads();
    // compact 5 slices -> slice 0
    for (int e = t; e < 2208; e += TPB) {
        smem0[e] = smem0[e] + smem0[2208 + e] + smem0[2*2208 + e]
                 + smem0[3*2208 + e] + smem0[4*2208 + e];
    }
    __syncthreads();

    // transform: thread (oo = t>>5, k = t&31) -> S1/S2/S0, atomic into acc
    const int oo = t >> 5, k = t & 31;
    float* ab = acc + ((size_t)b * OO + oo) * 33;
    if (k < 16) {
        const int i = k >> 2, kk = k & 3;
        float s = 0.f, s0acc = 0.f;
        for (int cc = 0; cc < 32; cc++) {
            const float* mc = &smem0[cc * 69];
            const float* wc = wgt + cc * 160 + oo * 16 + kk;
            const float w0 = wc[0], w1 = wc[4], w2 = wc[8], w3 = wc[12];
            s += w0*mc[i*4+0] + w1*mc[i*4+1] + w2*mc[i*4+2] + w3*mc[i*4+3];
            if (k == 3) s += mc[65];
            if (k == 7) s += mc[66];
            if (k == 0) s0acc += mc[64];
        }
        atomicAdd(&ab[k], s);
        if (k == 0) atomicAdd(&ab[32], s0acc);
    } else {
        const int km = k - 16, i = km >> 2, kk = km & 3;
        float s = 0.f;
        for (int cc = 0; cc < 32; cc++) {
            const float* mc = &smem0[cc * 69];
            const float* mi = mc + 16 + i * 10;
            const float* wc = wgt + cc * 160 + oo * 16 + kk;
            const float w0 = wc[0], w1 = wc[4], w2 = wc[8], w3 = wc[12];
            float q = w0*(w0*mi[0] + 2.f*(w1*mi[1] + w2*mi[2] + w3*mi[3]))
                    + w1*(w1*mi[4] + 2.f*(w2*mi[5] + w3*mi[6]))
                    + w2*(w2*mi[7] + 2.f*w3*mi[8])
                    + w3*(w3*mi[9]);
            s += q;
            if (km == 3) s += 2.f*(w0*mc[56]+w1*mc[57]+w2*mc[58]+w3*mc[59]) + mc[67];
            if (km == 7) s += 2.f*(w0*mc[60]+w1*mc[61]+w2*mc[62]+w3*mc[63]) + mc[68];
        }
        atomicAdd(&ab[k], s);
    }
}

// ---------------- iters 1-2: R3 body + tree softmax + LDS epilogue ----------------
__global__ __launch_bounds__(TPB, 3) void fc_pass(
    const float* __restrict__ pose, const float* __restrict__ actv,
    const float* __restrict__ wgt,
    const float* __restrict__ muIn, const float* __restrict__ ivIn,
    const float* __restrict__ biIn,
    float* __restrict__ acc)
{
    __shared__ float smem[TPB * 33];   // logits use first 704 floats; epilogue table after

    const int t = threadIdx.x;
    const int c = t & 31;
    const int o = t >> 5;           // 0..9
    const int ss = blockIdx.x;      // == hi
    const int b  = blockIdx.y;

    float wr[16];
    {
        const float4* wp = (const float4*)(wgt + ((c * OO + o) << 4));
        float4 a0 = wp[0], a1 = wp[1], a2 = wp[2], a3 = wp[3];
        wr[0]=a0.x; wr[1]=a0.y; wr[2]=a0.z; wr[3]=a0.w;
        wr[4]=a1.x; wr[5]=a1.y; wr[6]=a1.z; wr[7]=a1.w;
        wr[8]=a2.x; wr[9]=a2.y; wr[10]=a2.z; wr[11]=a2.w;
        wr[12]=a3.x; wr[13]=a3.y; wr[14]=a3.z; wr[15]=a3.w;
    }

    float mu[16], iv[16], bias;
    {
        const float4* mp = (const float4*)(muIn + (((size_t)b * OO + o) << 4));
        const float4* vp = (const float4*)(ivIn + (((size_t)b * OO + o) << 4));
        float4 m0=mp[0], m1=mp[1], m2=mp[2], m3=mp[3];
        mu[0]=m0.x; mu[1]=m0.y; mu[2]=m0.z; mu[3]=m0.w;
        mu[4]=m1.x; mu[5]=m1.y; mu[6]=m1.z; mu[7]=m1.w;
        mu[8]=m2.x; mu[9]=m2.y; mu[10]=m2.z; mu[11]=m2.w;
        mu[12]=m3.x; mu[13]=m3.y; mu[14]=m3.z; mu[15]=m3.w;
        float4 v0=vp[0], v1=vp[1], v2=vp[2], v3=vp[3];
        iv[0]=v0.x; iv[1]=v0.y; iv[2]=v0.z; iv[3]=v0.w;
        iv[4]=v1.x; iv[5]=v1.y; iv[6]=v1.z; iv[7]=v1.w;
        iv[8]=v2.x; iv[9]=v2.y; iv[10]=v2.z; iv[11]=v2.w;
        iv[12]=v3.x; iv[13]=v3.y; iv[14]=v3.z; iv[15]=v3.w;
        bias = biIn[b * OO + o];
    }

    float S1[16], S2[16], S0 = 0.f;
    #pragma unroll
    for (int d = 0; d < 16; d++) { S1[d] = 0.f; S2[d] = 0.f; }

    const size_t baseN = (size_t)b * NN + ss * 448;
    const float offh = (ss + 0.5f) * (1.0f / 14.0f);

    for (int s = 0; s < NSTEP; s++) {
        const float offw = (s + 0.5f) * (1.0f / 14.0f);
        const int n = s * 32 + c;

        const float4* pp = (const float4*)(pose + (baseN + n) * 16);
        float4 q0 = pp[0], q1 = pp[1], q2 = pp[2], q3 = pp[3];
        const float a = actv[baseN + n];

        float p[16];
        p[0]=q0.x; p[1]=q0.y; p[2]=q0.z; p[3]=q0.w;
        p[4]=q1.x; p[5]=q1.y; p[6]=q1.z; p[7]=q1.w;
        p[8]=q2.x; p[9]=q2.y; p[10]=q2.z; p[11]=q2.w;
        p[12]=q3.x; p[13]=q3.y; p[14]=q3.z; p[15]=q3.w;

        float v[16];
        #pragma unroll
        for (int ii = 0; ii < 4; ii++) {
            #pragma unroll
            for (int kk = 0; kk < 4; kk++) {
                float vv = fmaf(p[ii*4+0], wr[0*4+kk],
                           fmaf(p[ii*4+1], wr[1*4+kk],
                           fmaf(p[ii*4+2], wr[2*4+kk],
                                p[ii*4+3] * wr[3*4+kk])));
                if (ii == 0 && kk == 3) vv += offw;
                if (ii == 1 && kk == 3) vv += offh;
                v[ii*4+kk] = vv;
            }
        }

        float sqa = 0.f, sqb = 0.f, sqc = 0.f, sqd = 0.f;
        #pragma unroll
        for (int ii = 0; ii < 4; ii++) {
            float d0 = v[ii*4+0] - mu[ii*4+0];
            float d1 = v[ii*4+1] - mu[ii*4+1];
            float d2 = v[ii*4+2] - mu[ii*4+2];
            float d3 = v[ii*4+3] - mu[ii*4+3];
            sqa = fmaf(d0*d0, iv[ii*4+0], sqa);
            sqb = fmaf(d1*d1, iv[ii*4+1], sqb);
            sqc = fmaf(d2*d2, iv[ii*4+2], sqc);
            sqd = fmaf(d3*d3, iv[ii*4+3], sqd);
        }
        const float lg = bias - 0.5f * ((sqa + sqb) + (sqc + sqd));
        smem[(s & 1) * 352 + c * 11 + o] = lg;
        __syncthreads();

        float lgs[OO];
        #pragma unroll
        for (int j = 0; j < OO; j++) lgs[j] = smem[(s & 1) * 352 + c * 11 + j];
        float m01 = fmaxf(lgs[0], lgs[1]), m23 = fmaxf(lgs[2], lgs[3]);
        float m45 = fmaxf(lgs[4], lgs[5]), m67 = fmaxf(lgs[6], lgs[7]);
        float m89 = fmaxf(lgs[8], lgs[9]);
        const float mx = fmaxf(fmaxf(fmaxf(m01, m23), fmaxf(m45, m67)), m89);
        float ef[OO];
        #pragma unroll
        for (int j = 0; j < OO; j++) ef[j] = __expf(lgs[j] - mx);
        float own = ef[0];
        #pragma unroll
        for (int j = 1; j < OO; j++) own = (j == o) ? ef[j] : own;
        float s01 = ef[0]+ef[1], s23 = ef[2]+ef[3], s45 = ef[4]+ef[5];
        float s67 = ef[6]+ef[7], s89 = ef[8]+ef[9];
        const float sum = ((s01+s23) + (s45+s67)) + s89;
        const float rr = own * a / sum;

        #pragma unroll
        for (int d = 0; d < 16; d++) {
            const float rv = rr * v[d];
            S1[d] += rv;
            S2[d] = fmaf(rv, v[d], S2[d]);
        }
        S0 += rr;
    }

    // epilogue: parallel LDS table reduction (replaces 165-shuffle butterfly)
    __syncthreads();                 // logits dead; reuse smem
    #pragma unroll
    for (int k = 0; k < 33; k++)
        smem[t * 33 + k] = (k < 16) ? S1[k] : ((k < 32) ? S2[k - 16] : S0);
    __syncthreads();
    for (int u = t; u < 330; u += TPB) {
        const int oo = u / 33, kk = u - 33 * oo;
        float s = 0.f;
        #pragma unroll
        for (int cc = 0; cc < 32; cc++) s += smem[(oo * 32 + cc) * 33 + kk];
        atomicAdd(acc + ((size_t)b * OO + oo) * 33 + kk, s);
    }
}

__global__ __launch_bounds__(256) void fc_stats(
    const float* __restrict__ acc, const float* __restrict__ beta_a,
    const float* __restrict__ beta_u,
    float* __restrict__ muOut, float* __restrict__ ivOut, float* __restrict__ biOut,
    float* __restrict__ out, float inv_temp, int final_it)
{
    const int t = threadIdx.x;
    const int b = blockIdx.x;
    if (t >= 160) return;
    const int o = t >> 4, d = t & 15;
    const float* ab = acc + ((size_t)b * OO + o) * 33;
    const float S1 = ab[d], S2 = ab[16 + d], S0 = ab[32];
    const float rs = S0 + EPSF;
    const float mu = S1 / rs;
    float vraw = fmaf(mu * mu, S0, fmaf(-2.f * mu, S1, S2));
    vraw = fmaxf(vraw, 0.f);
    const float var = vraw / rs + EPSF;
    const float lv = __logf(var);
    float sv = lv;
    #pragma unroll
    for (int off = 8; off >= 1; off >>= 1) sv += __shfl_xor(sv, off, 16);
    const float cost = rs * fmaf(0.5f, sv, 16.f * beta_u[o]);
    const float av = 1.f / (1.f + __expf(-inv_temp * (beta_a[o] - cost)));
    if (!final_it) {
        muOut[((size_t)b * OO + o) * 16 + d] = mu;
        ivOut[((size_t)b * OO + o) * 16 + d] = 1.f / var;
        if (d == 0) biOut[b * OO + o] = __logf(av + EPSF) - 0.5f * sv;
    } else {
        out[((size_t)b * OO + o) * 16 + d] = mu;               // pose_out (B,O,16)
        if (d == 0) out[BB * OO * 16 + b * OO + o] = av;       // act_out (B,O)
    }
}

extern "C" void kernel_launch(void* const* d_in, const int* in_sizes, int n_in,
                              void* d_out, int out_size, void* d_ws, size_t ws_size,
                              hipStream_t stream) {
    const float* pose   = (const float*)d_in[0];
    const float* actv   = (const float*)d_in[1];
    const float* wgt    = (const float*)d_in[2];
    const float* beta_a = (const float*)d_in[3];
    const float* beta_u = (const float*)d_in[4];
    float* out = (float*)d_out;
    float* ws  = (float*)d_ws;

    hipMemsetAsync(ws + OFF_ACC, 0, (size_t)3 * ACC_PER_IT * sizeof(float), stream);

    float* acc0 = ws + OFF_ACC;
    float* acc1 = ws + OFF_ACC + ACC_PER_IT;
    float* acc2 = ws + OFF_ACC + 2 * ACC_PER_IT;
    float* mu0 = ws + OFF_MU;            float* mu1 = ws + OFF_MU + 10240;
    float* iv0 = ws + OFF_IV;            float* iv1 = ws + OFF_IV + 10240;
    float* bi0 = ws + OFF_BI;            float* bi1 = ws + OFF_BI + 640;

    dim3 pblk(TPB);
    fc_pass0<<<dim3(7, BB), pblk, 0, stream>>>(pose, actv, wgt, acc0);
    fc_stats<<<BB, 256, 0, stream>>>(acc0, beta_a, beta_u, mu0, iv0, bi0, out, 1.0f, 0);
    fc_pass<<<dim3(SSL, BB), pblk, 0, stream>>>(pose, actv, wgt, mu0, iv0, bi0, acc1);
    fc_stats<<<BB, 256, 0, stream>>>(acc1, beta_a, beta_u, mu1, iv1, bi1, out, 2.0f, 0);
    fc_pass<<<dim3(SSL, BB), pblk, 0, stream>>>(pose, actv, wgt, mu1, iv1, bi1, acc2);
    fc_stats<<<BB, 256, 0, stream>>>(acc2, beta_a, beta_u, nullptr, nullptr, nullptr, out, 3.0f, 1);
}